// Round 6
// baseline (1468.168 us; speedup 1.0000x reference)
//
#include <hip/hip_runtime.h>
#include <stdint.h>

// PyramidGrid (instant-NGP hash grid, simplex/tetrahedral interp) forward.
// BATCH = 2^21 points, 16 levels, LEVEL_DIM=2, table rows = 7,114,752.
//
// R6: force memory-level parallelism with inline-asm register ties.
// R4/R5 post-mortem: VGPR stayed 36 — both the plain restructure and
// sched_barrier(0) failed to keep 32 gathers in flight (sched_barrier is
// nomem at IR level; loads sink past it before the machine scheduler runs).
// Now each 8-level group's 32 float2 gather results are passed through
// asm volatile "+v" operands: the RA must materialize all 64 floats before
// the asm, and all consumes must stay after it -> 32 loads in flight, one
// s_waitcnt, then register-only combine.

constexpr uint32_t kBatch = 1u << 21;

typedef float f32x2 __attribute__((ext_vector_type(2)));
typedef float f32x4 __attribute__((ext_vector_type(4)));

__global__ __launch_bounds__(256) void pyramid_fwd(
    const float* __restrict__ in,    // [B,3]
    const float* __restrict__ emb,   // [7114752,2]
    float* __restrict__ out)         // [B,32]
{
    const uint32_t b = blockIdx.x * 256u + threadIdx.x;

    const float x0 = in[3u * b + 0u];
    const float x1 = in[3u * b + 1u];
    const float x2 = in[3u * b + 2u];

    // cumulative row offsets (prev) and hash masks per level
    constexpr uint32_t PREV[16] = {
        0u, 4096u, 36864u, 299008u, 823296u, 1347584u, 1871872u, 2396160u,
        2920448u, 3444736u, 3969024u, 4493312u, 5017600u, 5541888u, 6066176u, 6590464u};
    constexpr uint32_t MASK[16] = {
        4095u, 32767u, 262143u, 524287u, 524287u, 524287u, 524287u, 524287u,
        524287u, 524287u, 524287u, 524287u, 524287u, 524287u, 524287u, 524287u};

#pragma unroll
    for (int g = 0; g < 2; ++g) {
        f32x2 e[8][4];                  // 32 gather results (64 VGPRs), static-indexed
        float sa[8], sb[8], sc[8];      // sorted fracs per level

        // Phase A: compute indices and ISSUE all 32 loads, no consumes yet.
#pragma unroll
        for (int k = 0; k < 8; ++k) {
            const int lvl = g * 8 + k;
            const float res = (float)(16 << lvl);
            const uint32_t mask = MASK[lvl];
            const uint32_t prev = PREV[lvl];

            const float fx0 = x0 * res;
            const float fx1 = x1 * res;
            const float fx2 = x2 * res;
            const int i0 = (int)fx0;          // trunc == floor (x >= 0)
            const int i1 = (int)fx1;
            const int i2 = (int)fx2;
            const float f0 = fx0 - (float)i0; // exact fp32, matches reference
            const float f1 = fx1 - (float)i1;
            const float f2 = fx2 - (float)i2;

            // stable ascending ranks (== inv_inds of stable argsort)
            const int r0 = (int)(f1 < f0) + (int)(f2 < f0);
            const int r1 = (int)(f0 < f1) + (int)(f2 < f1) + (int)(f0 == f1);
            const int r2 = (int)(f0 < f2) + (int)(f1 < f2) + (int)(f0 == f2) + (int)(f1 == f2);

            // sorted frac values (exact selections)
            sa[k] = fminf(fminf(f0, f1), f2);
            sc[k] = fmaxf(fmaxf(f0, f1), f2);
            sb[k] = __builtin_amdgcn_fmed3f(f0, f1, f2);

            // hash components (uint32 wrap multiply; PRIMES = {1, 2654435761, 805459861})
            const uint32_t A0 = (uint32_t)i0;
            const uint32_t A1 = A0 + 1u;
            const uint32_t B0 = (uint32_t)i1 * 2654435761u;
            const uint32_t B1 = ((uint32_t)i1 + 1u) * 2654435761u;
            const uint32_t C0 = (uint32_t)i2 * 805459861u;
            const uint32_t C1 = ((uint32_t)i2 + 1u) * 805459861u;

            const uint32_t h0 = A1 ^ B1 ^ C1;                                        // all +1
            const uint32_t h1 = (r0 >= 1 ? A1 : A0) ^ (r1 >= 1 ? B1 : B0) ^ (r2 >= 1 ? C1 : C0);
            const uint32_t h2 = (r0 >= 2 ? A1 : A0) ^ (r1 >= 2 ? B1 : B0) ^ (r2 >= 2 ? C1 : C0);
            const uint32_t h3 = A0 ^ B0 ^ C0;                                        // base

            e[k][0] = *reinterpret_cast<const f32x2*>(emb + 2u * ((h0 & mask) + prev));
            e[k][1] = *reinterpret_cast<const f32x2*>(emb + 2u * ((h1 & mask) + prev));
            e[k][2] = *reinterpret_cast<const f32x2*>(emb + 2u * ((h2 & mask) + prev));
            e[k][3] = *reinterpret_cast<const f32x2*>(emb + 2u * ((h3 & mask) + prev));
        }

        // Data-dependency fence: every load result must be in a VGPR here
        // (asm may read AND modify it), and every consume below must wait for
        // the asm. Forces 32 loads in flight with a single s_waitcnt.
        asm volatile(""
            : "+v"(e[0][0]), "+v"(e[0][1]), "+v"(e[0][2]), "+v"(e[0][3]),
              "+v"(e[1][0]), "+v"(e[1][1]), "+v"(e[1][2]), "+v"(e[1][3]),
              "+v"(e[2][0]), "+v"(e[2][1]), "+v"(e[2][2]), "+v"(e[2][3]),
              "+v"(e[3][0]), "+v"(e[3][1]), "+v"(e[3][2]), "+v"(e[3][3]));
        asm volatile(""
            : "+v"(e[4][0]), "+v"(e[4][1]), "+v"(e[4][2]), "+v"(e[4][3]),
              "+v"(e[5][0]), "+v"(e[5][1]), "+v"(e[5][2]), "+v"(e[5][3]),
              "+v"(e[6][0]), "+v"(e[6][1]), "+v"(e[6][2]), "+v"(e[6][3]),
              "+v"(e[7][0]), "+v"(e[7][1]), "+v"(e[7][2]), "+v"(e[7][3]));

        // Phase B: combine (register-only).
        float o8[16];
#pragma unroll
        for (int k = 0; k < 8; ++k) {
            const float w0 = sa[k];
            const float w1 = sb[k] - sa[k];
            const float w2 = sc[k] - sb[k];
            const float w3 = 1.0f - sc[k];
            o8[2 * k + 0] = w0 * e[k][0].x + w1 * e[k][1].x + w2 * e[k][2].x + w3 * e[k][3].x;
            o8[2 * k + 1] = w0 * e[k][0].y + w1 * e[k][1].y + w2 * e[k][2].y + w3 * e[k][3].y;
        }

        // Phase C: 64B contiguous store per lane.
        f32x4* o = reinterpret_cast<f32x4*>(out + (size_t)b * 32u + (size_t)g * 16u);
#pragma unroll
        for (int q = 0; q < 4; ++q) {
            f32x4 v;
            v.x = o8[4 * q + 0];
            v.y = o8[4 * q + 1];
            v.z = o8[4 * q + 2];
            v.w = o8[4 * q + 3];
            o[q] = v;
        }
    }
}

extern "C" void kernel_launch(void* const* d_in, const int* in_sizes, int n_in,
                              void* d_out, int out_size, void* d_ws, size_t ws_size,
                              hipStream_t stream) {
    const float* in  = (const float*)d_in[0];
    const float* emb = (const float*)d_in[1];
    float* out = (float*)d_out;

    dim3 grid(kBatch / 256u);
    dim3 block(256u);
    hipLaunchKernelGGL(pyramid_fwd, grid, block, 0, stream, in, emb, out);
}

// Round 7
// 816.260 us; speedup vs baseline: 1.7987x; 1.7987x over previous
//
#include <hip/hip_runtime.h>
#include <stdint.h>

// PyramidGrid (instant-NGP hash grid, simplex interp) forward — R7.
//
// History: R1-R6 all pinned at 3.8-3.9 TB/s effective with 4.6-5.8 GB of line
// fetch per dispatch (57MB table, reuse ~80x uncaptured). NT hints (R2) and
// MLP scaling (R6: VGPR 68, 3.5x outstanding) changed nothing -> random-line
// service path saturated; traffic itself must drop. Hash kills spatial
// locality, so the only capturable structure is: ONE level's table (<=4MB)
// fits a per-XCD L2. R7 phases the op by level: 16 per-level gather kernels
// (table L2-resident, coalesced 8B scratch writes) + 2 transpose kernels
// (8 levels -> 64B full-line out chunks). Scratch: 8 slabs x B x 2 f32 =
// 128 MiB in d_ws; falls back to the R4 monolithic kernel if ws is smaller.

constexpr uint32_t kBatch   = 1u << 21;
constexpr uint32_t kQuarter = kBatch / 4u;          // points per k-step in gather
constexpr size_t   kSlab    = (size_t)kBatch * 2u;  // floats per level slab

typedef float f32x2 __attribute__((ext_vector_type(2)));
typedef float f32x4 __attribute__((ext_vector_type(4)));

// cumulative row offsets (prev) and pow2 hash masks per level
constexpr uint32_t PREV[16] = {
    0u, 4096u, 36864u, 299008u, 823296u, 1347584u, 1871872u, 2396160u,
    2920448u, 3444736u, 3969024u, 4493312u, 5017600u, 5541888u, 6066176u, 6590464u};
constexpr uint32_t MASK[16] = {
    4095u, 32767u, 262143u, 524287u, 524287u, 524287u, 524287u, 524287u,
    524287u, 524287u, 524287u, 524287u, 524287u, 524287u, 524287u, 524287u};

// Shared per-point math (verified bit-exact vs reference in R1-R6).
__device__ __forceinline__ void corner_hashes_weights(
    float x0, float x1, float x2, float res, uint32_t mask, uint32_t prev,
    uint32_t& g0, uint32_t& g1, uint32_t& g2, uint32_t& g3,
    float& sa, float& sb, float& sc)
{
    const float fx0 = x0 * res;
    const float fx1 = x1 * res;
    const float fx2 = x2 * res;
    const int i0 = (int)fx0;            // trunc == floor (x >= 0)
    const int i1 = (int)fx1;
    const int i2 = (int)fx2;
    const float f0 = fx0 - (float)i0;   // exact fp32
    const float f1 = fx1 - (float)i1;
    const float f2 = fx2 - (float)i2;

    // stable ascending ranks (== inv_inds of stable argsort)
    const int r0 = (int)(f1 < f0) + (int)(f2 < f0);
    const int r1 = (int)(f0 < f1) + (int)(f2 < f1) + (int)(f0 == f1);
    const int r2 = (int)(f0 < f2) + (int)(f1 < f2) + (int)(f0 == f2) + (int)(f1 == f2);

    sa = fminf(fminf(f0, f1), f2);
    sc = fmaxf(fmaxf(f0, f1), f2);
    sb = __builtin_amdgcn_fmed3f(f0, f1, f2);

    // hash components (uint32 wrap multiply; PRIMES = {1, 2654435761, 805459861})
    const uint32_t A0 = (uint32_t)i0;
    const uint32_t A1 = A0 + 1u;
    const uint32_t B0 = (uint32_t)i1 * 2654435761u;
    const uint32_t B1 = ((uint32_t)i1 + 1u) * 2654435761u;
    const uint32_t C0 = (uint32_t)i2 * 805459861u;
    const uint32_t C1 = ((uint32_t)i2 + 1u) * 805459861u;

    const uint32_t h0 = A1 ^ B1 ^ C1;
    const uint32_t h1 = (r0 >= 1 ? A1 : A0) ^ (r1 >= 1 ? B1 : B0) ^ (r2 >= 1 ? C1 : C0);
    const uint32_t h2 = (r0 >= 2 ? A1 : A0) ^ (r1 >= 2 ? B1 : B0) ^ (r2 >= 2 ? C1 : C0);
    const uint32_t h3 = A0 ^ B0 ^ C0;

    g0 = (h0 & mask) + prev;
    g1 = (h1 & mask) + prev;
    g2 = (h2 & mask) + prev;
    g3 = (h3 & mask) + prev;
}

// ---------------- Phase kernels: one level at a time ----------------

template <int LVL>
__global__ __launch_bounds__(256) void gather_level(
    const float* __restrict__ in,    // [B,3]
    const float* __restrict__ emb,   // [7114752,2]
    float* __restrict__ scr)         // this level's slab: [B,2]
{
    const uint32_t tid = blockIdx.x * 256u + threadIdx.x;
    const float res = (float)(16 << LVL);
    const uint32_t mask = MASK[LVL];
    const uint32_t prev = PREV[LVL];

    f32x2 e[4][4];
    float sa[4], sb[4], sc[4];

    // Phase A: 4 points/thread -> issue all 16 gathers (L2-hit class latency).
#pragma unroll
    for (int k = 0; k < 4; ++k) {
        const uint32_t b = tid + (uint32_t)k * kQuarter;
        const float x0 = __builtin_nontemporal_load(in + 3u * b + 0u);
        const float x1 = __builtin_nontemporal_load(in + 3u * b + 1u);
        const float x2 = __builtin_nontemporal_load(in + 3u * b + 2u);
        uint32_t g0, g1, g2, g3;
        corner_hashes_weights(x0, x1, x2, res, mask, prev, g0, g1, g2, g3,
                              sa[k], sb[k], sc[k]);
        e[k][0] = *reinterpret_cast<const f32x2*>(emb + 2u * g0);
        e[k][1] = *reinterpret_cast<const f32x2*>(emb + 2u * g1);
        e[k][2] = *reinterpret_cast<const f32x2*>(emb + 2u * g2);
        e[k][3] = *reinterpret_cast<const f32x2*>(emb + 2u * g3);
    }

    // Keep all 16 loads in flight (R6-proven data-dependency fence).
    asm volatile(""
        : "+v"(e[0][0]), "+v"(e[0][1]), "+v"(e[0][2]), "+v"(e[0][3]),
          "+v"(e[1][0]), "+v"(e[1][1]), "+v"(e[1][2]), "+v"(e[1][3]),
          "+v"(e[2][0]), "+v"(e[2][1]), "+v"(e[2][2]), "+v"(e[2][3]),
          "+v"(e[3][0]), "+v"(e[3][1]), "+v"(e[3][2]), "+v"(e[3][3]));

    // Phase B: combine + coalesced 8B/lane stores into the slab.
#pragma unroll
    for (int k = 0; k < 4; ++k) {
        const float w0 = sa[k];
        const float w1 = sb[k] - sa[k];
        const float w2 = sc[k] - sb[k];
        const float w3 = 1.0f - sc[k];
        f32x2 v;
        v.x = w0 * e[k][0].x + w1 * e[k][1].x + w2 * e[k][2].x + w3 * e[k][3].x;
        v.y = w0 * e[k][0].y + w1 * e[k][1].y + w2 * e[k][2].y + w3 * e[k][3].y;
        const uint32_t b = tid + (uint32_t)k * kQuarter;
        *reinterpret_cast<f32x2*>(scr + 2u * (size_t)b) = v;
    }
}

// Assemble 8 level slabs -> contiguous 64B (one full line) per point.
__global__ __launch_bounds__(256) void transpose8(
    const float* __restrict__ scr,   // [8][B][2]
    float* __restrict__ out,         // [B,32]
    uint32_t half)                   // 0: levels 0-7, 1: levels 8-15
{
    const uint32_t b = blockIdx.x * 256u + threadIdx.x;
    float v[16];
#pragma unroll
    for (int l = 0; l < 8; ++l) {
        const f32x2 e = __builtin_nontemporal_load(
            reinterpret_cast<const f32x2*>(scr + (size_t)l * kSlab + 2u * (size_t)b));
        v[2 * l + 0] = e.x;
        v[2 * l + 1] = e.y;
    }
    float* o = out + (size_t)b * 32u + (size_t)half * 16u;
#pragma unroll
    for (int q = 0; q < 4; ++q) {
        f32x4 t;
        t.x = v[4 * q + 0];
        t.y = v[4 * q + 1];
        t.z = v[4 * q + 2];
        t.w = v[4 * q + 3];
        *reinterpret_cast<f32x4*>(o + 4 * q) = t;
    }
}

// ---------------- Fallback: R4 monolithic (best single-kernel, 1267us) -----

__global__ __launch_bounds__(256) void pyramid_fwd_mono(
    const float* __restrict__ in,
    const float* __restrict__ emb,
    float* __restrict__ out)
{
    const uint32_t b = blockIdx.x * 256u + threadIdx.x;
    const float x0 = in[3u * b + 0u];
    const float x1 = in[3u * b + 1u];
    const float x2 = in[3u * b + 2u];

#pragma unroll
    for (int g = 0; g < 2; ++g) {
        float o8[16];
#pragma unroll
        for (int k = 0; k < 8; ++k) {
            const int lvl = g * 8 + k;
            const float res = (float)(16 << lvl);
            uint32_t g0, g1, g2, g3;
            float sa, sb, sc;
            corner_hashes_weights(x0, x1, x2, res, MASK[lvl], PREV[lvl],
                                  g0, g1, g2, g3, sa, sb, sc);
            const f32x2 e0 = *reinterpret_cast<const f32x2*>(emb + 2u * g0);
            const f32x2 e1 = *reinterpret_cast<const f32x2*>(emb + 2u * g1);
            const f32x2 e2 = *reinterpret_cast<const f32x2*>(emb + 2u * g2);
            const f32x2 e3 = *reinterpret_cast<const f32x2*>(emb + 2u * g3);
            const float w0 = sa, w1 = sb - sa, w2 = sc - sb, w3 = 1.0f - sc;
            o8[2 * k + 0] = w0 * e0.x + w1 * e1.x + w2 * e2.x + w3 * e3.x;
            o8[2 * k + 1] = w0 * e0.y + w1 * e1.y + w2 * e2.y + w3 * e3.y;
        }
        f32x4* o = reinterpret_cast<f32x4*>(out + (size_t)b * 32u + (size_t)g * 16u);
#pragma unroll
        for (int q = 0; q < 4; ++q) {
            f32x4 v;
            v.x = o8[4 * q + 0];
            v.y = o8[4 * q + 1];
            v.z = o8[4 * q + 2];
            v.w = o8[4 * q + 3];
            o[q] = v;
        }
    }
}

// ---------------- Launch ----------------

extern "C" void kernel_launch(void* const* d_in, const int* in_sizes, int n_in,
                              void* d_out, int out_size, void* d_ws, size_t ws_size,
                              hipStream_t stream) {
    const float* in  = (const float*)d_in[0];
    const float* emb = (const float*)d_in[1];
    float* out = (float*)d_out;

    const size_t need = (size_t)8 * kSlab * sizeof(float);  // 128 MiB
    if (ws_size >= need) {
        float* scr = (float*)d_ws;
        dim3 gb(kQuarter / 256u), tb(256u), gt(kBatch / 256u);
#define GL(L, S) hipLaunchKernelGGL(gather_level<L>, gb, tb, 0, stream, in, emb, scr + (size_t)(S) * kSlab)
        GL(0, 0); GL(1, 1); GL(2, 2); GL(3, 3);
        GL(4, 4); GL(5, 5); GL(6, 6); GL(7, 7);
        hipLaunchKernelGGL(transpose8, gt, tb, 0, stream, scr, out, 0u);
        GL(8, 0); GL(9, 1); GL(10, 2); GL(11, 3);
        GL(12, 4); GL(13, 5); GL(14, 6); GL(15, 7);
        hipLaunchKernelGGL(transpose8, gt, tb, 0, stream, scr, out, 1u);
#undef GL
    } else {
        dim3 grid(kBatch / 256u), block(256u);
        hipLaunchKernelGGL(pyramid_fwd_mono, grid, block, 0, stream, in, emb, out);
    }
}

// Round 8
// 726.124 us; speedup vs baseline: 2.0219x; 1.1241x over previous
//
#include <hip/hip_runtime.h>
#include <stdint.h>

// PyramidGrid (instant-NGP hash grid, simplex interp) forward — R8.
//
// R7 (level-phased: 16 gather kernels + 2 transposes) = 1267 -> 816us.
// R8: (1) fuse gathers into 2 kernels (lvl = blockIdx.x>>11; a level's 2048
// blocks ~= chip co-resident capacity so levels still run ~serially, keeping
// each 4MB table L2-resident) -> 4 dispatches total, restores top-5 counter
// visibility; (2) NT cache policy on full-line-per-wave streams only (input
// loads, scratch stores) so streaming doesn't evict the table from L2.
// Out stores stay cached (R2: NT on partial-line stores amplified writes 2.4x).

constexpr uint32_t kBatch   = 1u << 21;
constexpr uint32_t kQuarter = kBatch / 4u;          // points per k-step in gather
constexpr size_t   kSlab    = (size_t)kBatch * 2u;  // floats per level slab

typedef float f32x2 __attribute__((ext_vector_type(2)));
typedef float f32x4 __attribute__((ext_vector_type(4)));

// cumulative row offsets (prev) and pow2 hash masks per level
constexpr uint32_t PREV[16] = {
    0u, 4096u, 36864u, 299008u, 823296u, 1347584u, 1871872u, 2396160u,
    2920448u, 3444736u, 3969024u, 4493312u, 5017600u, 5541888u, 6066176u, 6590464u};
constexpr uint32_t MASK[16] = {
    4095u, 32767u, 262143u, 524287u, 524287u, 524287u, 524287u, 524287u,
    524287u, 524287u, 524287u, 524287u, 524287u, 524287u, 524287u, 524287u};

// Shared per-point math (verified bit-exact vs reference in R1-R7).
__device__ __forceinline__ void corner_hashes_weights(
    float x0, float x1, float x2, float res, uint32_t mask, uint32_t prev,
    uint32_t& g0, uint32_t& g1, uint32_t& g2, uint32_t& g3,
    float& sa, float& sb, float& sc)
{
    const float fx0 = x0 * res;
    const float fx1 = x1 * res;
    const float fx2 = x2 * res;
    const int i0 = (int)fx0;            // trunc == floor (x >= 0)
    const int i1 = (int)fx1;
    const int i2 = (int)fx2;
    const float f0 = fx0 - (float)i0;   // exact fp32
    const float f1 = fx1 - (float)i1;
    const float f2 = fx2 - (float)i2;

    // stable ascending ranks (== inv_inds of stable argsort)
    const int r0 = (int)(f1 < f0) + (int)(f2 < f0);
    const int r1 = (int)(f0 < f1) + (int)(f2 < f1) + (int)(f0 == f1);
    const int r2 = (int)(f0 < f2) + (int)(f1 < f2) + (int)(f0 == f2) + (int)(f1 == f2);

    sa = fminf(fminf(f0, f1), f2);
    sc = fmaxf(fmaxf(f0, f1), f2);
    sb = __builtin_amdgcn_fmed3f(f0, f1, f2);

    // hash components (uint32 wrap multiply; PRIMES = {1, 2654435761, 805459861})
    const uint32_t A0 = (uint32_t)i0;
    const uint32_t A1 = A0 + 1u;
    const uint32_t B0 = (uint32_t)i1 * 2654435761u;
    const uint32_t B1 = ((uint32_t)i1 + 1u) * 2654435761u;
    const uint32_t C0 = (uint32_t)i2 * 805459861u;
    const uint32_t C1 = ((uint32_t)i2 + 1u) * 805459861u;

    const uint32_t h0 = A1 ^ B1 ^ C1;
    const uint32_t h1 = (r0 >= 1 ? A1 : A0) ^ (r1 >= 1 ? B1 : B0) ^ (r2 >= 1 ? C1 : C0);
    const uint32_t h2 = (r0 >= 2 ? A1 : A0) ^ (r1 >= 2 ? B1 : B0) ^ (r2 >= 2 ? C1 : C0);
    const uint32_t h3 = A0 ^ B0 ^ C0;

    g0 = (h0 & mask) + prev;
    g1 = (h1 & mask) + prev;
    g2 = (h2 & mask) + prev;
    g3 = (h3 & mask) + prev;
}

// ---------------- Fused per-level gather: 8 levels per launch ----------------
// blockIdx.x in [0, 8*2048): lvl = base + (bid >> 11). HW dispatches blocks in
// index order; one level's 2048 blocks ~= co-resident capacity, so levels run
// approximately serially -> the active level's <=4MB table stays L2-resident.

__global__ __launch_bounds__(256) void gather8(
    const float* __restrict__ in,    // [B,3]
    const float* __restrict__ emb,   // [7114752,2]
    float* __restrict__ scr,         // [8][B][2]
    uint32_t base)                   // 0 or 8
{
    const uint32_t bid  = blockIdx.x;
    const uint32_t lvl  = base + (bid >> 11);
    const uint32_t blk  = bid & 2047u;
    const uint32_t tid  = blk * 256u + threadIdx.x;

    const float res = (float)(16u << lvl);
    const uint32_t mask = MASK[lvl];
    const uint32_t prev = PREV[lvl];
    float* slab = scr + (size_t)(lvl - base) * kSlab;

    f32x2 e[4][4];
    float sa[4], sb[4], sc[4];

    // Phase A: 4 points/thread -> issue all 16 gathers.
#pragma unroll
    for (int k = 0; k < 4; ++k) {
        const uint32_t b = tid + (uint32_t)k * kQuarter;
        const float x0 = __builtin_nontemporal_load(in + 3u * b + 0u);
        const float x1 = __builtin_nontemporal_load(in + 3u * b + 1u);
        const float x2 = __builtin_nontemporal_load(in + 3u * b + 2u);
        uint32_t g0, g1, g2, g3;
        corner_hashes_weights(x0, x1, x2, res, mask, prev, g0, g1, g2, g3,
                              sa[k], sb[k], sc[k]);
        e[k][0] = *reinterpret_cast<const f32x2*>(emb + 2u * g0);
        e[k][1] = *reinterpret_cast<const f32x2*>(emb + 2u * g1);
        e[k][2] = *reinterpret_cast<const f32x2*>(emb + 2u * g2);
        e[k][3] = *reinterpret_cast<const f32x2*>(emb + 2u * g3);
    }

    // Keep all 16 loads in flight (R6-proven data-dependency fence).
    asm volatile(""
        : "+v"(e[0][0]), "+v"(e[0][1]), "+v"(e[0][2]), "+v"(e[0][3]),
          "+v"(e[1][0]), "+v"(e[1][1]), "+v"(e[1][2]), "+v"(e[1][3]),
          "+v"(e[2][0]), "+v"(e[2][1]), "+v"(e[2][2]), "+v"(e[2][3]),
          "+v"(e[3][0]), "+v"(e[3][1]), "+v"(e[3][2]), "+v"(e[3][3]));

    // Phase B: combine + coalesced 8B/lane NT stores (512B/wave full lines,
    // no-allocate keeps L2 for the table).
#pragma unroll
    for (int k = 0; k < 4; ++k) {
        const float w0 = sa[k];
        const float w1 = sb[k] - sa[k];
        const float w2 = sc[k] - sb[k];
        const float w3 = 1.0f - sc[k];
        f32x2 v;
        v.x = w0 * e[k][0].x + w1 * e[k][1].x + w2 * e[k][2].x + w3 * e[k][3].x;
        v.y = w0 * e[k][0].y + w1 * e[k][1].y + w2 * e[k][2].y + w3 * e[k][3].y;
        const uint32_t b = tid + (uint32_t)k * kQuarter;
        __builtin_nontemporal_store(v, reinterpret_cast<f32x2*>(slab + 2u * (size_t)b));
    }
}

// Assemble 8 level slabs -> contiguous 64B (one full line) per point.
__global__ __launch_bounds__(256) void transpose8(
    const float* __restrict__ scr,   // [8][B][2]
    float* __restrict__ out,         // [B,32]
    uint32_t half)                   // 0: levels 0-7, 1: levels 8-15
{
    const uint32_t b = blockIdx.x * 256u + threadIdx.x;
    float v[16];
#pragma unroll
    for (int l = 0; l < 8; ++l) {
        const f32x2 e = __builtin_nontemporal_load(
            reinterpret_cast<const f32x2*>(scr + (size_t)l * kSlab + 2u * (size_t)b));
        v[2 * l + 0] = e.x;
        v[2 * l + 1] = e.y;
    }
    // Cached (non-NT) stores: per-instruction a wave touches 64 partial lines;
    // L2 merges q=0..3 into full lines (R2 lesson).
    float* o = out + (size_t)b * 32u + (size_t)half * 16u;
#pragma unroll
    for (int q = 0; q < 4; ++q) {
        f32x4 t;
        t.x = v[4 * q + 0];
        t.y = v[4 * q + 1];
        t.z = v[4 * q + 2];
        t.w = v[4 * q + 3];
        *reinterpret_cast<f32x4*>(o + 4 * q) = t;
    }
}

// ---------------- Fallback: monolithic (if ws too small) ----------------

__global__ __launch_bounds__(256) void pyramid_fwd_mono(
    const float* __restrict__ in,
    const float* __restrict__ emb,
    float* __restrict__ out)
{
    const uint32_t b = blockIdx.x * 256u + threadIdx.x;
    const float x0 = in[3u * b + 0u];
    const float x1 = in[3u * b + 1u];
    const float x2 = in[3u * b + 2u];

#pragma unroll
    for (int g = 0; g < 2; ++g) {
        float o8[16];
#pragma unroll
        for (int k = 0; k < 8; ++k) {
            const int lvl = g * 8 + k;
            const float res = (float)(16 << lvl);
            uint32_t g0, g1, g2, g3;
            float sa, sb, sc;
            corner_hashes_weights(x0, x1, x2, res, MASK[lvl], PREV[lvl],
                                  g0, g1, g2, g3, sa, sb, sc);
            const f32x2 e0 = *reinterpret_cast<const f32x2*>(emb + 2u * g0);
            const f32x2 e1 = *reinterpret_cast<const f32x2*>(emb + 2u * g1);
            const f32x2 e2 = *reinterpret_cast<const f32x2*>(emb + 2u * g2);
            const f32x2 e3 = *reinterpret_cast<const f32x2*>(emb + 2u * g3);
            const float w0 = sa, w1 = sb - sa, w2 = sc - sb, w3 = 1.0f - sc;
            o8[2 * k + 0] = w0 * e0.x + w1 * e1.x + w2 * e2.x + w3 * e3.x;
            o8[2 * k + 1] = w0 * e0.y + w1 * e1.y + w2 * e2.y + w3 * e3.y;
        }
        f32x4* o = reinterpret_cast<f32x4*>(out + (size_t)b * 32u + (size_t)g * 16u);
#pragma unroll
        for (int q = 0; q < 4; ++q) {
            f32x4 v;
            v.x = o8[4 * q + 0];
            v.y = o8[4 * q + 1];
            v.z = o8[4 * q + 2];
            v.w = o8[4 * q + 3];
            o[q] = v;
        }
    }
}

// ---------------- Launch ----------------

extern "C" void kernel_launch(void* const* d_in, const int* in_sizes, int n_in,
                              void* d_out, int out_size, void* d_ws, size_t ws_size,
                              hipStream_t stream) {
    const float* in  = (const float*)d_in[0];
    const float* emb = (const float*)d_in[1];
    float* out = (float*)d_out;

    const size_t need = (size_t)8 * kSlab * sizeof(float);  // 128 MiB
    if (ws_size >= need) {
        float* scr = (float*)d_ws;
        dim3 gg(8u * 2048u), tb(256u), gt(kBatch / 256u);
        hipLaunchKernelGGL(gather8, gg, tb, 0, stream, in, emb, scr, 0u);
        hipLaunchKernelGGL(transpose8, gt, tb, 0, stream, scr, out, 0u);
        hipLaunchKernelGGL(gather8, gg, tb, 0, stream, in, emb, scr, 8u);
        hipLaunchKernelGGL(transpose8, gt, tb, 0, stream, scr, out, 1u);
    } else {
        dim3 grid(kBatch / 256u), block(256u);
        hipLaunchKernelGGL(pyramid_fwd_mono, grid, block, 0, stream, in, emb, out);
    }
}